// Round 10
// baseline (170.143 us; speedup 1.0000x reference)
//
#include <hip/hip_runtime.h>

#define K_CLASSES 32
#define D 128
#define EPSv 0.5f
#define ZPAD 42   // shorts per row: 21 dwords, coprime with 32 banks
#define WIN 4096  // window rows per list build (list LDS capacity)
#define MPB 2     // matrices per chol block

typedef __attribute__((ext_vector_type(8))) short short8;
typedef __attribute__((ext_vector_type(4))) float f32x4;

// fp32 -> bf16 round-to-nearest-even
static __device__ inline unsigned short f2bf(float f) {
  union { float f; unsigned u; } x; x.f = f;
  unsigned r = x.u + 0x7FFFu + ((x.u >> 16) & 1u);
  return (unsigned short)(r >> 16);
}

// ---------------------------------------------------------------------------
// Partial per-class Gram via bf16 MFMA. Grid (nchunk, K); block (c,k) handles
// rows [c*chunkRows, (c+1)*chunkRows) of class k, writes a partial Gram.
// Deterministic (wave-scan list build, owner writes, no float atomics).
// Global loads pipelined 2 stages ahead (named A/B buffers, static indexing).
// ---------------------------------------------------------------------------
__global__ __launch_bounds__(256) void class_gram_kernel(
    const float* __restrict__ Z, const int* __restrict__ Y,
    float* __restrict__ part, int* __restrict__ counts_part,
    float* __restrict__ percls_part, int m, int chunkRows) {
  const int k = blockIdx.y;
  const int c = blockIdx.x;
  const int tid = threadIdx.x;
  const int lane = tid & 63;
  const int w = tid >> 6;

  const int rowStart = c * chunkRows;
  const int rowEnd = min(m, rowStart + chunkRows);

  __shared__ int list[WIN];
  __shared__ unsigned short zs[128][ZPAD];  // [feature][sample] bf16
  __shared__ int wsum[4];

  const int p = tid >> 4;      // sample-pair index 0..15
  const int part16 = tid & 15; // feature group: part16*8 .. part16*8+7
  const int l15 = lane & 15;
  const int kb = (lane >> 4) * 8;
  const int rb0 = w * 2, rb1 = w * 2 + 1;

  f32x4 acc0[8], acc1[8];
#pragma unroll
  for (int cb = 0; cb < 8; ++cb) { acc0[cb] = (f32x4)(0.f); acc1[cb] = (f32x4)(0.f); }
  float colacc[8];
#pragma unroll
  for (int j = 0; j < 8; ++j) colacc[j] = 0.f;

  int matched = 0;

#define LOAD_STAGE(d0, d1, stidx)                                   \
  {                                                                 \
    _Pragma("unroll") for (int j = 0; j < 8; ++j) { d0[j] = 0.f; d1[j] = 0.f; } \
    if ((stidx) < nst) {                                            \
      const int i0 = ((stidx) << 5) + p * 2;                        \
      const int r0 = list[i0];                                      \
      const int r1 = list[i0 + 1];                                  \
      if (r0 >= 0) {                                                \
        const float* zp = Z + (size_t)r0 * D + part16 * 8;          \
        *(float4*)&d0[0] = *(const float4*)zp;                      \
        *(float4*)&d0[4] = *(const float4*)(zp + 4);                \
      }                                                             \
      if (r1 >= 0) {                                                \
        const float* zp = Z + (size_t)r1 * D + part16 * 8;          \
        *(float4*)&d1[0] = *(const float4*)zp;                      \
        *(float4*)&d1[4] = *(const float4*)(zp + 4);                \
      }                                                             \
    }                                                               \
  }

#define STAGE_BODY(s0, s1)                                          \
  {                                                                 \
    _Pragma("unroll") for (int j = 0; j < 8; ++j) colacc[j] += s0[j] + s1[j]; \
    __syncthreads();                                                \
    _Pragma("unroll") for (int j = 0; j < 8; ++j) {                 \
      const unsigned pk = (unsigned)f2bf(s0[j]) | ((unsigned)f2bf(s1[j]) << 16); \
      *(unsigned*)&zs[part16 * 8 + j][2 * p] = pk;                  \
    }                                                               \
    __syncthreads();                                                \
  }

#define MFMA_BODY()                                                 \
  {                                                                 \
    short8 fragC[8];                                                \
    _Pragma("unroll") for (int fb = 0; fb < 8; ++fb)                \
      fragC[fb] = *(const short8*)&zs[fb * 16 + l15][kb];           \
    const short8 fragR0 = *(const short8*)&zs[rb0 * 16 + l15][kb];  \
    const short8 fragR1 = *(const short8*)&zs[rb1 * 16 + l15][kb];  \
    _Pragma("unroll") for (int cb = 0; cb < 8; ++cb) {              \
      acc0[cb] = __builtin_amdgcn_mfma_f32_16x16x32_bf16(fragR0, fragC[cb], acc0[cb], 0, 0, 0); \
      acc1[cb] = __builtin_amdgcn_mfma_f32_16x16x32_bf16(fragR1, fragC[cb], acc1[cb], 0, 0, 0); \
    }                                                               \
  }

  for (int w0 = rowStart; w0 < rowEnd; w0 += WIN) {
    const int wend = min(w0 + WIN, rowEnd);
    __syncthreads();  // prior window's list readers done

    // ---- phase 1: build row list for class k in [w0, wend) ----
    int run = 0;
    for (int base = w0; base < wend; base += 2048) {
      const int start = base + tid * 8;
      int yv[8];
      if (((start & 3) == 0) && start + 8 <= wend) {
        const int4 ya = *(const int4*)(Y + start);
        const int4 yb = *(const int4*)(Y + start + 4);
        yv[0] = ya.x; yv[1] = ya.y; yv[2] = ya.z; yv[3] = ya.w;
        yv[4] = yb.x; yv[5] = yb.y; yv[6] = yb.z; yv[7] = yb.w;
      } else {
#pragma unroll
        for (int e = 0; e < 8; ++e) {
          const int r = start + e;
          yv[e] = (r < wend) ? Y[r] : -1;
        }
      }
      int cnt = 0;
#pragma unroll
      for (int e = 0; e < 8; ++e) cnt += (yv[e] == k) ? 1 : 0;
      int cs = cnt;
#pragma unroll
      for (int off = 1; off < 64; off <<= 1) {
        const int nbr = __shfl_up(cs, off);
        if (lane >= off) cs += nbr;
      }
      if (lane == 63) wsum[w] = cs;
      const int excl = cs - cnt;
      __syncthreads();
      int woff = 0, ctot = 0;
#pragma unroll
      for (int ww = 0; ww < 4; ++ww) {
        const int v = wsum[ww];
        if (ww < w) woff += v;
        ctot += v;
      }
      __syncthreads();
      int pos = run + woff + excl;
#pragma unroll
      for (int e = 0; e < 8; ++e) {
        if (yv[e] == k) { list[pos] = start + e; ++pos; }
      }
      run += ctot;
    }
    const int total = run;
    matched += total;
    const int padded = (total + 31) & ~31;
    for (int i = total + tid; i < padded; i += 256) list[i] = -1;
    __syncthreads();

    // ---- phase 2: staged bf16 MFMA, 2-stage-deep prefetch ----
    const int nst = padded >> 5;
    float vA0[8], vA1[8], vB0[8], vB1[8];
    LOAD_STAGE(vA0, vA1, 0);
    LOAD_STAGE(vB0, vB1, 1);

    for (int st = 0; st < nst; st += 2) {
      STAGE_BODY(vA0, vA1);
      LOAD_STAGE(vA0, vA1, st + 2);   // overlap with MFMA + next stage phase1
      MFMA_BODY();
      if (st + 1 < nst) {
        STAGE_BODY(vB0, vB1);
        LOAD_STAGE(vB0, vB1, st + 3);
        MFMA_BODY();
      }
    }
  }

  // ---- write partial Gram (owner writes, no atomics) ----
  float* dst = part + ((size_t)c * K_CLASSES + k) * (D * D);
  const int l4 = lane >> 4;
#pragma unroll
  for (int cb = 0; cb < 8; ++cb)
#pragma unroll
    for (int q = 0; q < 4; ++q) {
      dst[(rb0 * 16 + l4 * 4 + q) * D + cb * 16 + l15] = acc0[cb][q];
      dst[(rb1 * 16 + l4 * 4 + q) * D + cb * 16 + l15] = acc1[cb][q];
    }

  // ---- partial column sums (deterministic LDS reduce, reuse zs) ----
  __syncthreads();
  float* cred = (float*)&zs[0][0];  // 16*128 floats = 8 KB
#pragma unroll
  for (int j = 0; j < 8; ++j) cred[p * 128 + part16 * 8 + j] = colacc[j];
  __syncthreads();
  if (tid < 128) {
    float s = 0.f;
#pragma unroll
    for (int pp = 0; pp < 16; ++pp) s += cred[pp * 128 + tid];
    percls_part[(c * K_CLASSES + k) * D + tid] = s;
  }
  if (tid == 0) counts_part[c * K_CLASSES + k] = matched;
}

// ---------------------------------------------------------------------------
// R1: ztpiz[k][e] = sum_c part[c][k][e], float4-vectorized. Grid (16, K).
// Deterministic order; safe when part aliases ztpiz (nchunk==1).
// ---------------------------------------------------------------------------
__global__ __launch_bounds__(256) void reduce1_kernel(
    const float4* __restrict__ part, float4* __restrict__ ztpiz, int nchunk) {
  const int k = blockIdx.y;
  const int e = blockIdx.x * 256 + threadIdx.x;  // float4 index, D*D/4 = 4096
  float4 s = make_float4(0.f, 0.f, 0.f, 0.f);
  for (int c = 0; c < nchunk; ++c) {
    const float4 v = part[((size_t)c * K_CLASSES + k) * (D * D / 4) + e];
    s.x += v.x; s.y += v.y; s.z += v.z; s.w += v.w;
  }
  ztpiz[(size_t)k * (D * D / 4) + e] = s;
}

// ---------------------------------------------------------------------------
// R2: blocks 0..63: gram[e] = sum_k ztpiz[k][e] (L2-hot).
//     block 64: Z_mean -> out (8 independent accumulator chains), counts.
// ---------------------------------------------------------------------------
__global__ __launch_bounds__(256) void reduce2_kernel(
    const float* __restrict__ ztpiz, float* __restrict__ gram,
    const int* __restrict__ counts_part, int* __restrict__ counts_total,
    const float* __restrict__ percls_part, float* __restrict__ zmean_out,
    int nchunk, int m) {
  if (blockIdx.x < 64) {
    const int e = blockIdx.x * 256 + threadIdx.x;
    float g = 0.f;
#pragma unroll
    for (int k = 0; k < K_CLASSES; ++k) g += ztpiz[(size_t)k * D * D + e];
    gram[e] = g;
  } else {
    __shared__ float buf[256];
    const int col = threadIdx.x & 127;
    const int half = threadIdx.x >> 7;
    const int np = nchunk * K_CLASSES;
    float s0 = 0.f, s1 = 0.f, s2 = 0.f, s3 = 0.f;
    float s4 = 0.f, s5 = 0.f, s6 = 0.f, s7 = 0.f;
    int i = half;
    for (; i + 14 < np; i += 16) {
      s0 += percls_part[(i)*D + col];
      s1 += percls_part[(i + 2) * D + col];
      s2 += percls_part[(i + 4) * D + col];
      s3 += percls_part[(i + 6) * D + col];
      s4 += percls_part[(i + 8) * D + col];
      s5 += percls_part[(i + 10) * D + col];
      s6 += percls_part[(i + 12) * D + col];
      s7 += percls_part[(i + 14) * D + col];
    }
    for (; i < np; i += 2) s0 += percls_part[i * D + col];
    buf[threadIdx.x] = ((s0 + s1) + (s2 + s3)) + ((s4 + s5) + (s6 + s7));
    __syncthreads();
    if (threadIdx.x < 128)
      zmean_out[threadIdx.x] = (buf[threadIdx.x] + buf[threadIdx.x + 128]) / (float)m;
    if (threadIdx.x < K_CLASSES) {
      int t = 0;
      for (int c = 0; c < nchunk; ++c) t += counts_part[c * K_CLASSES + threadIdx.x];
      counts_total[threadIdx.x] = t;
    }
  }
}

// ---------------------------------------------------------------------------
// Blocked register-tile Cholesky of I + s*G (rank-8 right-looking).
// MPB=2 matrices per block, __launch_bounds__(512, 1): min-waves/EU=1 lifts
// the register-allocator occupancy target so the 8x8 tile stays in VGPRs
// (r7/r9 failure signature: VGPR pinned 128 + 196KB scratch WRITE_SIZE).
// HW co-residency of the 8-wave block still caps VGPR at 256 - enough.
// 2 waves/SIMD => cross-matrix latency hiding between the two matrices.
// ---------------------------------------------------------------------------
__global__ __launch_bounds__(512, 1) void chol_kernel(const float* __restrict__ ztpiz,
                                                      const float* __restrict__ gram,
                                                      const int* __restrict__ counts,
                                                      float* __restrict__ ld, int m) {
  const int lm = threadIdx.x >> 8;            // local matrix 0..MPB-1
  const int b = blockIdx.x * MPB + lm;        // global matrix 0..33
  const bool active = (b <= K_CLASSES);
  const int t = threadIdx.x & 255;

  __shared__ float panT[MPB][8][132];  // [mat][p][row] transposed panel
  __shared__ float l11[MPB][8][8];
  __shared__ float invd[MPB][8];
  __shared__ float red[MPB][256];

  const float* src;
  float s;
  if (b == 0 || !active) {
    src = gram;
    s = active ? (float)D / ((float)m * EPSv) : 0.f;
  } else {
    src = ztpiz + (size_t)(b - 1) * D * D;
    const float cf = (float)counts[b - 1] + 1e-8f;
    s = (float)D / (cf * EPSv);
  }
  const int tr = t >> 4;
  const int tc = t & 15;
  const int R = tr * 8, C = tc * 8;

  float a[8][8];
#pragma unroll
  for (int i = 0; i < 8; ++i) {
    const float* sp = src + (size_t)(R + i) * D + C;
    float tv[8];
    *(float4*)&tv[0] = *(const float4*)sp;
    *(float4*)&tv[4] = *(const float4*)(sp + 4);
#pragma unroll
    for (int j = 0; j < 8; ++j)
      a[i][j] = s * tv[j] + ((R + i) == (C + j) ? 1.0f : 0.0f);
  }

  for (int ct = 0; ct < 16; ++ct) {
    // --- 1. diagonal 8x8 factor (one owner thread per matrix, divide-free) ---
    if (tr == ct && tc == ct) {
      float dr[8];
#pragma unroll
      for (int kk = 0; kk < 8; ++kk) {
        const float x = a[kk][kk];
        const float r = rsqrtf(x);
        const float lkk = x * r;
        a[kk][kk] = lkk;
        dr[kk] = r;
#pragma unroll
        for (int i = 0; i < 8; ++i)
          if (i > kk) a[i][kk] *= r;
#pragma unroll
        for (int j = 0; j < 8; ++j)
          if (j > kk)
#pragma unroll
            for (int i = 0; i < 8; ++i)
              if (i >= j) a[i][j] = fmaf(-a[i][kk], a[j][kk], a[i][j]);
      }
#pragma unroll
      for (int i = 0; i < 8; ++i) {
#pragma unroll
        for (int j = 0; j < 8; ++j)
          if (j <= i) l11[lm][i][j] = a[i][j];
        invd[lm][i] = dr[i];
      }
    }
    __syncthreads();  // A: l11/invd visible; prior panT readers done

    // --- 2. panel solve: L21 = A21 * L11^-T ---
    if (tc == ct && tr > ct) {
#pragma unroll
      for (int j = 0; j < 8; ++j) {
#pragma unroll
        for (int i = 0; i < 8; ++i) {
          float x = a[i][j];
#pragma unroll
          for (int pq = 0; pq < 8; ++pq)
            if (pq < j) x = fmaf(-a[i][pq], l11[lm][j][pq], x);
          a[i][j] = x * invd[lm][j];
        }
      }
#pragma unroll
      for (int pq = 0; pq < 8; ++pq) {
        float t8[8];
#pragma unroll
        for (int i = 0; i < 8; ++i) t8[i] = a[i][pq];
        *(float4*)&panT[lm][pq][R] = *(float4*)&t8[0];
        *(float4*)&panT[lm][pq][R + 4] = *(float4*)&t8[4];
      }
    }
    __syncthreads();  // B: panel visible

    // --- 3. rank-8 trailing update ---
    if (tr > ct && tc > ct) {
#pragma unroll
      for (int pq = 0; pq < 8; ++pq) {
        float cr8[8], cc8[8];
        *(float4*)&cr8[0] = *(const float4*)&panT[lm][pq][R];
        *(float4*)&cr8[4] = *(const float4*)&panT[lm][pq][R + 4];
        *(float4*)&cc8[0] = *(const float4*)&panT[lm][pq][C];
        *(float4*)&cc8[4] = *(const float4*)&panT[lm][pq][C + 4];
#pragma unroll
        for (int i = 0; i < 8; ++i)
#pragma unroll
          for (int j = 0; j < 8; ++j)
            a[i][j] = fmaf(-cr8[i], cc8[j], a[i][j]);
      }
    }
  }

  float lsum = 0.f;
  if (tr == tc) {
#pragma unroll
    for (int i = 0; i < 8; ++i) lsum += logf(a[i][i]);
  }
  red[lm][t] = lsum;
  __syncthreads();
  for (int off = 128; off > 0; off >>= 1) {
    if (t < off) red[lm][t] += red[lm][t + off];
    __syncthreads();
  }
  if (t == 0 && active) ld[b] = 2.0f * red[lm][0];
}

// ---------------------------------------------------------------------------
// Loss scalar only (Z_mean handled in reduce2). One wave.
// ---------------------------------------------------------------------------
__global__ void finalize_kernel(const float* __restrict__ ldv,
                                const int* __restrict__ counts,
                                float* __restrict__ out, int m) {
  const int lane = threadIdx.x & 63;
  float v = 0.f;
  if (lane < K_CLASSES)
    v = ldv[lane + 1] * (((float)counts[lane] + 1e-8f) / (float)m);
#pragma unroll
  for (int off = 32; off > 0; off >>= 1) v += __shfl_down(v, off);
  if (lane == 0) out[0] = -0.5f * ldv[0] + 0.5f * v;
}

extern "C" void kernel_launch(void* const* d_in, const int* in_sizes, int n_in,
                              void* d_out, int out_size, void* d_ws, size_t ws_size,
                              hipStream_t stream) {
  const float* Z = (const float*)d_in[0];
  const int* Y = (const int*)d_in[1];
  float* out = (float*)d_out;
  const int m = in_sizes[0] / D;

  float* ztpiz = out + 1;  // (K, D, D)

  // choose nchunk by workspace capacity (deterministic given ws_size)
  const size_t perChunk = (size_t)K_CLASSES * D * D * sizeof(float);  // 2 MB
  int nchunk = 32;
  for (;; nchunk >>= 1) {
    const size_t need = (size_t)nchunk * perChunk +
                        (size_t)nchunk * K_CLASSES * (D + 1) * sizeof(float) +
                        K_CLASSES * sizeof(int) + 64 * 1024 + 4096;
    if (nchunk == 1 || need <= ws_size) break;
  }

  char* wsb = (char*)d_ws;
  float* part = (nchunk == 1) ? ztpiz : (float*)wsb;
  size_t off = (nchunk == 1) ? 0 : (size_t)nchunk * perChunk;
  float* percls_part = (float*)(wsb + off); off += (size_t)nchunk * K_CLASSES * D * sizeof(float);
  int* counts_part = (int*)(wsb + off);     off += (size_t)nchunk * K_CLASSES * sizeof(int);
  int* counts_total = (int*)(wsb + off);    off += K_CLASSES * sizeof(int);
  float* ld = (float*)(wsb + off);          off += 64 * sizeof(float);
  float* gram = (float*)(wsb + ((off + 255) & ~(size_t)255));

  const int chunkRows = (m + nchunk - 1) / nchunk;

  class_gram_kernel<<<dim3(nchunk, K_CLASSES), 256, 0, stream>>>(
      Z, Y, part, counts_part, percls_part, m, chunkRows);
  reduce1_kernel<<<dim3(D * D / 4 / 256, K_CLASSES), 256, 0, stream>>>(
      (const float4*)part, (float4*)ztpiz, nchunk);
  reduce2_kernel<<<65, 256, 0, stream>>>(ztpiz, gram, counts_part, counts_total,
                                         percls_part, out + 1 + K_CLASSES * D * D,
                                         nchunk, m);
  chol_kernel<<<(K_CLASSES + MPB) / MPB, MPB * 256, 0, stream>>>(
      ztpiz, gram, counts_total, ld, m);
  finalize_kernel<<<1, 64, 0, stream>>>(ld, counts_total, out, m);
}

// Round 11
// 109.653 us; speedup vs baseline: 1.5517x; 1.5517x over previous
//
#include <hip/hip_runtime.h>

#define K_CLASSES 32
#define D 128
#define EPSv 0.5f
#define ZPAD 42   // shorts per row: 21 dwords, coprime with 32 banks
#define WIN 4096  // window rows per list build (list LDS capacity)

typedef __attribute__((ext_vector_type(8))) short short8;
typedef __attribute__((ext_vector_type(4))) float f32x4;

// fp32 -> bf16 round-to-nearest-even
static __device__ inline unsigned short f2bf(float f) {
  union { float f; unsigned u; } x; x.f = f;
  unsigned r = x.u + 0x7FFFu + ((x.u >> 16) & 1u);
  return (unsigned short)(r >> 16);
}

// ---------------------------------------------------------------------------
// Partial per-class Gram via bf16 MFMA. Grid (nchunk, K); block (c,k) handles
// rows [c*chunkRows, (c+1)*chunkRows) of class k, writes a partial Gram.
// Deterministic (wave-scan list build, owner writes, no float atomics).
// Global loads pipelined 2 stages ahead (named A/B buffers, static indexing).
// ---------------------------------------------------------------------------
__global__ __launch_bounds__(256) void class_gram_kernel(
    const float* __restrict__ Z, const int* __restrict__ Y,
    float* __restrict__ part, int* __restrict__ counts_part,
    float* __restrict__ percls_part, int m, int chunkRows) {
  const int k = blockIdx.y;
  const int c = blockIdx.x;
  const int tid = threadIdx.x;
  const int lane = tid & 63;
  const int w = tid >> 6;

  const int rowStart = c * chunkRows;
  const int rowEnd = min(m, rowStart + chunkRows);

  __shared__ int list[WIN];
  __shared__ unsigned short zs[128][ZPAD];  // [feature][sample] bf16
  __shared__ int wsum[4];

  const int p = tid >> 4;      // sample-pair index 0..15
  const int part16 = tid & 15; // feature group: part16*8 .. part16*8+7
  const int l15 = lane & 15;
  const int kb = (lane >> 4) * 8;
  const int rb0 = w * 2, rb1 = w * 2 + 1;

  f32x4 acc0[8], acc1[8];
#pragma unroll
  for (int cb = 0; cb < 8; ++cb) { acc0[cb] = (f32x4)(0.f); acc1[cb] = (f32x4)(0.f); }
  float colacc[8];
#pragma unroll
  for (int j = 0; j < 8; ++j) colacc[j] = 0.f;

  int matched = 0;

#define LOAD_STAGE(d0, d1, stidx)                                   \
  {                                                                 \
    _Pragma("unroll") for (int j = 0; j < 8; ++j) { d0[j] = 0.f; d1[j] = 0.f; } \
    if ((stidx) < nst) {                                            \
      const int i0 = ((stidx) << 5) + p * 2;                        \
      const int r0 = list[i0];                                      \
      const int r1 = list[i0 + 1];                                  \
      if (r0 >= 0) {                                                \
        const float* zp = Z + (size_t)r0 * D + part16 * 8;          \
        *(float4*)&d0[0] = *(const float4*)zp;                      \
        *(float4*)&d0[4] = *(const float4*)(zp + 4);                \
      }                                                             \
      if (r1 >= 0) {                                                \
        const float* zp = Z + (size_t)r1 * D + part16 * 8;          \
        *(float4*)&d1[0] = *(const float4*)zp;                      \
        *(float4*)&d1[4] = *(const float4*)(zp + 4);                \
      }                                                             \
    }                                                               \
  }

#define STAGE_BODY(s0, s1)                                          \
  {                                                                 \
    _Pragma("unroll") for (int j = 0; j < 8; ++j) colacc[j] += s0[j] + s1[j]; \
    __syncthreads();                                                \
    _Pragma("unroll") for (int j = 0; j < 8; ++j) {                 \
      const unsigned pk = (unsigned)f2bf(s0[j]) | ((unsigned)f2bf(s1[j]) << 16); \
      *(unsigned*)&zs[part16 * 8 + j][2 * p] = pk;                  \
    }                                                               \
    __syncthreads();                                                \
  }

#define MFMA_BODY()                                                 \
  {                                                                 \
    short8 fragC[8];                                                \
    _Pragma("unroll") for (int fb = 0; fb < 8; ++fb)                \
      fragC[fb] = *(const short8*)&zs[fb * 16 + l15][kb];           \
    const short8 fragR0 = *(const short8*)&zs[rb0 * 16 + l15][kb];  \
    const short8 fragR1 = *(const short8*)&zs[rb1 * 16 + l15][kb];  \
    _Pragma("unroll") for (int cb = 0; cb < 8; ++cb) {              \
      acc0[cb] = __builtin_amdgcn_mfma_f32_16x16x32_bf16(fragR0, fragC[cb], acc0[cb], 0, 0, 0); \
      acc1[cb] = __builtin_amdgcn_mfma_f32_16x16x32_bf16(fragR1, fragC[cb], acc1[cb], 0, 0, 0); \
    }                                                               \
  }

  for (int w0 = rowStart; w0 < rowEnd; w0 += WIN) {
    const int wend = min(w0 + WIN, rowEnd);
    __syncthreads();  // prior window's list readers done

    // ---- phase 1: build row list for class k in [w0, wend) ----
    int run = 0;
    for (int base = w0; base < wend; base += 2048) {
      const int start = base + tid * 8;
      int yv[8];
      if (((start & 3) == 0) && start + 8 <= wend) {
        const int4 ya = *(const int4*)(Y + start);
        const int4 yb = *(const int4*)(Y + start + 4);
        yv[0] = ya.x; yv[1] = ya.y; yv[2] = ya.z; yv[3] = ya.w;
        yv[4] = yb.x; yv[5] = yb.y; yv[6] = yb.z; yv[7] = yb.w;
      } else {
#pragma unroll
        for (int e = 0; e < 8; ++e) {
          const int r = start + e;
          yv[e] = (r < wend) ? Y[r] : -1;
        }
      }
      int cnt = 0;
#pragma unroll
      for (int e = 0; e < 8; ++e) cnt += (yv[e] == k) ? 1 : 0;
      int cs = cnt;
#pragma unroll
      for (int off = 1; off < 64; off <<= 1) {
        const int nbr = __shfl_up(cs, off);
        if (lane >= off) cs += nbr;
      }
      if (lane == 63) wsum[w] = cs;
      const int excl = cs - cnt;
      __syncthreads();
      int woff = 0, ctot = 0;
#pragma unroll
      for (int ww = 0; ww < 4; ++ww) {
        const int v = wsum[ww];
        if (ww < w) woff += v;
        ctot += v;
      }
      __syncthreads();
      int pos = run + woff + excl;
#pragma unroll
      for (int e = 0; e < 8; ++e) {
        if (yv[e] == k) { list[pos] = start + e; ++pos; }
      }
      run += ctot;
    }
    const int total = run;
    matched += total;
    const int padded = (total + 31) & ~31;
    for (int i = total + tid; i < padded; i += 256) list[i] = -1;
    __syncthreads();

    // ---- phase 2: staged bf16 MFMA, 2-stage-deep prefetch ----
    const int nst = padded >> 5;
    float vA0[8], vA1[8], vB0[8], vB1[8];
    LOAD_STAGE(vA0, vA1, 0);
    LOAD_STAGE(vB0, vB1, 1);

    for (int st = 0; st < nst; st += 2) {
      STAGE_BODY(vA0, vA1);
      LOAD_STAGE(vA0, vA1, st + 2);   // overlap with MFMA + next stage phase1
      MFMA_BODY();
      if (st + 1 < nst) {
        STAGE_BODY(vB0, vB1);
        LOAD_STAGE(vB0, vB1, st + 3);
        MFMA_BODY();
      }
    }
  }

  // ---- write partial Gram (owner writes, no atomics) ----
  float* dst = part + ((size_t)c * K_CLASSES + k) * (D * D);
  const int l4 = lane >> 4;
#pragma unroll
  for (int cb = 0; cb < 8; ++cb)
#pragma unroll
    for (int q = 0; q < 4; ++q) {
      dst[(rb0 * 16 + l4 * 4 + q) * D + cb * 16 + l15] = acc0[cb][q];
      dst[(rb1 * 16 + l4 * 4 + q) * D + cb * 16 + l15] = acc1[cb][q];
    }

  // ---- partial column sums (deterministic LDS reduce, reuse zs) ----
  __syncthreads();
  float* cred = (float*)&zs[0][0];  // 16*128 floats = 8 KB
#pragma unroll
  for (int j = 0; j < 8; ++j) cred[p * 128 + part16 * 8 + j] = colacc[j];
  __syncthreads();
  if (tid < 128) {
    float s = 0.f;
#pragma unroll
    for (int pp = 0; pp < 16; ++pp) s += cred[pp * 128 + tid];
    percls_part[(c * K_CLASSES + k) * D + tid] = s;
  }
  if (tid == 0) counts_part[c * K_CLASSES + k] = matched;
}

// ---------------------------------------------------------------------------
// R1: ztpiz[k][e] = sum_c part[c][k][e], float4-vectorized. Grid (16, K).
// Deterministic order; safe when part aliases ztpiz (nchunk==1).
// ---------------------------------------------------------------------------
__global__ __launch_bounds__(256) void reduce1_kernel(
    const float4* __restrict__ part, float4* __restrict__ ztpiz, int nchunk) {
  const int k = blockIdx.y;
  const int e = blockIdx.x * 256 + threadIdx.x;  // float4 index, D*D/4 = 4096
  float4 s = make_float4(0.f, 0.f, 0.f, 0.f);
  for (int c = 0; c < nchunk; ++c) {
    const float4 v = part[((size_t)c * K_CLASSES + k) * (D * D / 4) + e];
    s.x += v.x; s.y += v.y; s.z += v.z; s.w += v.w;
  }
  ztpiz[(size_t)k * (D * D / 4) + e] = s;
}

// ---------------------------------------------------------------------------
// R2: blocks 0..63: gram[e] = sum_k ztpiz[k][e] (L2-hot).
//     block 64: Z_mean -> out (8 independent accumulator chains), counts.
// ---------------------------------------------------------------------------
__global__ __launch_bounds__(256) void reduce2_kernel(
    const float* __restrict__ ztpiz, float* __restrict__ gram,
    const int* __restrict__ counts_part, int* __restrict__ counts_total,
    const float* __restrict__ percls_part, float* __restrict__ zmean_out,
    int nchunk, int m) {
  if (blockIdx.x < 64) {
    const int e = blockIdx.x * 256 + threadIdx.x;
    float g = 0.f;
#pragma unroll
    for (int k = 0; k < K_CLASSES; ++k) g += ztpiz[(size_t)k * D * D + e];
    gram[e] = g;
  } else {
    __shared__ float buf[256];
    const int col = threadIdx.x & 127;
    const int half = threadIdx.x >> 7;
    const int np = nchunk * K_CLASSES;
    float s0 = 0.f, s1 = 0.f, s2 = 0.f, s3 = 0.f;
    float s4 = 0.f, s5 = 0.f, s6 = 0.f, s7 = 0.f;
    int i = half;
    for (; i + 14 < np; i += 16) {
      s0 += percls_part[(i)*D + col];
      s1 += percls_part[(i + 2) * D + col];
      s2 += percls_part[(i + 4) * D + col];
      s3 += percls_part[(i + 6) * D + col];
      s4 += percls_part[(i + 8) * D + col];
      s5 += percls_part[(i + 10) * D + col];
      s6 += percls_part[(i + 12) * D + col];
      s7 += percls_part[(i + 14) * D + col];
    }
    for (; i < np; i += 2) s0 += percls_part[i * D + col];
    buf[threadIdx.x] = ((s0 + s1) + (s2 + s3)) + ((s4 + s5) + (s6 + s7));
    __syncthreads();
    if (threadIdx.x < 128)
      zmean_out[threadIdx.x] = (buf[threadIdx.x] + buf[threadIdx.x + 128]) / (float)m;
    if (threadIdx.x < K_CLASSES) {
      int t = 0;
      for (int c = 0; c < nchunk; ++c) t += counts_part[c * K_CLASSES + threadIdx.x];
      counts_total[threadIdx.x] = t;
    }
  }
}

// ---------------------------------------------------------------------------
// Blocked Cholesky of I + s*G, rank-8 right-looking, ONE matrix per
// 512-thread block (8 waves = 2 waves/SIMD TLP). Per-thread tile is 4x8
// (32 VGPR) so the kernel fits the hard 128-VGPR cap of 512-thread blocks
// (r7/r9/r10 lesson: 8x8 tiles at 512 threads ALWAYS spill, 196KB scratch).
// Diag 8x8 factored by one thread from LDS using a 36-entry lower-triangle
// register array (static indices). Diagonals go to diagv[] in LDS.
// 3 barriers per block-step.
// ---------------------------------------------------------------------------
#define TRI(i, j) ((i) * ((i) + 1) / 2 + (j))
__global__ __launch_bounds__(512) void chol_kernel(const float* __restrict__ ztpiz,
                                                   const float* __restrict__ gram,
                                                   const int* __restrict__ counts,
                                                   float* __restrict__ ld, int m) {
  const int b = blockIdx.x;
  __shared__ float diag8[8][8];   // staging for the current diagonal block
  __shared__ float l11s[8][8];    // factored L11 (lower triangle used)
  __shared__ float invd[8];
  __shared__ float diagv[D];      // all factored diagonal entries
  __shared__ float panT[8][132];  // [p][row] transposed panel
  __shared__ float red[128];

  const float* src;
  float s;
  if (b == 0) {
    src = gram;
    s = (float)D / ((float)m * EPSv);
  } else {
    src = ztpiz + (size_t)(b - 1) * D * D;
    const float cf = (float)counts[b - 1] + 1e-8f;
    s = (float)D / (cf * EPSv);
  }
  const int tid = threadIdx.x;
  const int tr = tid >> 4;   // 0..31, rows 4tr..4tr+3
  const int tc = tid & 15;   // 0..15, cols 8tc..8tc+7
  const int R = tr * 4, C = tc * 8;

  float a[4][8];
#pragma unroll
  for (int i = 0; i < 4; ++i) {
    const float* sp = src + (size_t)(R + i) * D + C;
    float tv[8];
    *(float4*)&tv[0] = *(const float4*)sp;
    *(float4*)&tv[4] = *(const float4*)(sp + 4);
#pragma unroll
    for (int j = 0; j < 8; ++j)
      a[i][j] = s * tv[j] + ((R + i) == (C + j) ? 1.0f : 0.0f);
  }

  for (int ct = 0; ct < 16; ++ct) {
    // --- phase 0: the two diag-owner threads post their 4x8 halves ---
    if (tc == ct && (tr == 2 * ct || tr == 2 * ct + 1)) {
      const int hb = (tr - 2 * ct) * 4;  // LDS row base (runtime addr ok)
#pragma unroll
      for (int i = 0; i < 4; ++i) {
        *(float4*)&diag8[hb + i][0] = *(float4*)&a[i][0];
        *(float4*)&diag8[hb + i][4] = *(float4*)&a[i][4];
      }
    }
    __syncthreads();  // A

    // --- phase 1: one thread factors the 8x8 (lower triangle in 36 regs) ---
    if (tc == ct && tr == 2 * ct) {
      float f[36], dr[8];
#pragma unroll
      for (int i = 0; i < 8; ++i)
#pragma unroll
        for (int j = 0; j < 8; ++j)
          if (j <= i) f[TRI(i, j)] = diag8[i][j];
#pragma unroll
      for (int kk = 0; kk < 8; ++kk) {
        const float x = f[TRI(kk, kk)];
        const float r = rsqrtf(x);
        f[TRI(kk, kk)] = x * r;
        dr[kk] = r;
#pragma unroll
        for (int i = 0; i < 8; ++i)
          if (i > kk) f[TRI(i, kk)] *= r;
#pragma unroll
        for (int j = 0; j < 8; ++j)
          if (j > kk)
#pragma unroll
            for (int i = 0; i < 8; ++i)
              if (i >= j) f[TRI(i, j)] = fmaf(-f[TRI(i, kk)], f[TRI(j, kk)], f[TRI(i, j)]);
      }
#pragma unroll
      for (int i = 0; i < 8; ++i) {
#pragma unroll
        for (int j = 0; j < 8; ++j)
          if (j <= i) l11s[i][j] = f[TRI(i, j)];
        invd[i] = dr[i];
        diagv[8 * ct + i] = f[TRI(i, i)];
      }
    }
    __syncthreads();  // B

    // --- phase 2: panel solve, 4 rows per thread (col ct, rows below diag) ---
    if (tc == ct && tr >= 2 * ct + 2) {
#pragma unroll
      for (int j = 0; j < 8; ++j) {
#pragma unroll
        for (int i = 0; i < 4; ++i) {
          float x = a[i][j];
#pragma unroll
          for (int q = 0; q < 8; ++q)
            if (q < j) x = fmaf(-a[i][q], l11s[j][q], x);
          a[i][j] = x * invd[j];
        }
      }
#pragma unroll
      for (int pq = 0; pq < 8; ++pq) {
        float t4[4];
#pragma unroll
        for (int i = 0; i < 4; ++i) t4[i] = a[i][pq];
        *(float4*)&panT[pq][R] = *(float4*)&t4[0];
      }
    }
    __syncthreads();  // C

    // --- phase 3: rank-8 trailing update (4x8 per thread) ---
    if (tr >= 2 * ct + 2 && tc >= ct + 1) {
#pragma unroll 4
      for (int pq = 0; pq < 8; ++pq) {
        float cr4[4], cc8[8];
        *(float4*)&cr4[0] = *(const float4*)&panT[pq][R];
        *(float4*)&cc8[0] = *(const float4*)&panT[pq][C];
        *(float4*)&cc8[4] = *(const float4*)&panT[pq][C + 4];
#pragma unroll
        for (int i = 0; i < 4; ++i)
#pragma unroll
          for (int j = 0; j < 8; ++j)
            a[i][j] = fmaf(-cr4[i], cc8[j], a[i][j]);
      }
    }
  }

  // --- logdet from diagv (all writes ordered before the last barriers) ---
  if (tid < 128) red[tid] = logf(diagv[tid]);
  __syncthreads();
  for (int off = 64; off > 0; off >>= 1) {
    if (tid < off) red[tid] += red[tid + off];
    __syncthreads();
  }
  if (tid == 0) ld[b] = 2.0f * red[0];
}

// ---------------------------------------------------------------------------
// Loss scalar only (Z_mean handled in reduce2). One wave.
// ---------------------------------------------------------------------------
__global__ void finalize_kernel(const float* __restrict__ ldv,
                                const int* __restrict__ counts,
                                float* __restrict__ out, int m) {
  const int lane = threadIdx.x & 63;
  float v = 0.f;
  if (lane < K_CLASSES)
    v = ldv[lane + 1] * (((float)counts[lane] + 1e-8f) / (float)m);
#pragma unroll
  for (int off = 32; off > 0; off >>= 1) v += __shfl_down(v, off);
  if (lane == 0) out[0] = -0.5f * ldv[0] + 0.5f * v;
}

extern "C" void kernel_launch(void* const* d_in, const int* in_sizes, int n_in,
                              void* d_out, int out_size, void* d_ws, size_t ws_size,
                              hipStream_t stream) {
  const float* Z = (const float*)d_in[0];
  const int* Y = (const int*)d_in[1];
  float* out = (float*)d_out;
  const int m = in_sizes[0] / D;

  float* ztpiz = out + 1;  // (K, D, D)

  // choose nchunk by workspace capacity (deterministic given ws_size)
  const size_t perChunk = (size_t)K_CLASSES * D * D * sizeof(float);  // 2 MB
  int nchunk = 32;
  for (;; nchunk >>= 1) {
    const size_t need = (size_t)nchunk * perChunk +
                        (size_t)nchunk * K_CLASSES * (D + 1) * sizeof(float) +
                        K_CLASSES * sizeof(int) + 64 * 1024 + 4096;
    if (nchunk == 1 || need <= ws_size) break;
  }

  char* wsb = (char*)d_ws;
  float* part = (nchunk == 1) ? ztpiz : (float*)wsb;
  size_t off = (nchunk == 1) ? 0 : (size_t)nchunk * perChunk;
  float* percls_part = (float*)(wsb + off); off += (size_t)nchunk * K_CLASSES * D * sizeof(float);
  int* counts_part = (int*)(wsb + off);     off += (size_t)nchunk * K_CLASSES * sizeof(int);
  int* counts_total = (int*)(wsb + off);    off += K_CLASSES * sizeof(int);
  float* ld = (float*)(wsb + off);          off += 64 * sizeof(float);
  float* gram = (float*)(wsb + ((off + 255) & ~(size_t)255));

  const int chunkRows = (m + nchunk - 1) / nchunk;

  class_gram_kernel<<<dim3(nchunk, K_CLASSES), 256, 0, stream>>>(
      Z, Y, part, counts_part, percls_part, m, chunkRows);
  reduce1_kernel<<<dim3(D * D / 4 / 256, K_CLASSES), 256, 0, stream>>>(
      (const float4*)part, (float4*)ztpiz, nchunk);
  reduce2_kernel<<<65, 256, 0, stream>>>(ztpiz, gram, counts_part, counts_total,
                                         percls_part, out + 1 + K_CLASSES * D * D,
                                         nchunk, m);
  chol_kernel<<<K_CLASSES + 1, 512, 0, stream>>>(ztpiz, gram, counts_total, ld, m);
  finalize_kernel<<<1, 64, 0, stream>>>(ld, counts_total, out, m);
}